// Round 1
// baseline (98.317 us; speedup 1.0000x reference)
//
#include <hip/hip_runtime.h>
#include <hip/hip_bf16.h>
#include <stdint.h>

#define BATCH 8
#define NNODE 1024
#define INF 768
#define OUTF 512
#define MTOT (BATCH * NNODE) /* 8192 */

typedef __attribute__((ext_vector_type(8))) short short8;
typedef __attribute__((ext_vector_type(4))) float floatx4;

__device__ __forceinline__ unsigned short f2bf(float f) {
  union { float f; unsigned u; } v; v.f = f;
  unsigned r = v.u + 0x7fffu + ((v.u >> 16) & 1u);
  return (unsigned short)(r >> 16);
}

// ---------------- W (768x512 f32) -> Wt (512x768 bf16) ----------------
__global__ __launch_bounds__(256) void transposeW_kernel(
    const float* __restrict__ W, short* __restrict__ Wt) {
  __shared__ float tile[32][33];
  int o0 = blockIdx.x * 32;   // 16 blocks over OUTF
  int k0 = blockIdx.y * 32;   // 24 blocks over INF
  int x = threadIdx.x & 31, y = threadIdx.x >> 5;  // y in [0,8)
#pragma unroll
  for (int q = 0; q < 4; ++q) {
    int r = y * 4 + q;
    tile[r][x] = W[(size_t)(k0 + r) * OUTF + o0 + x];
  }
  __syncthreads();
#pragma unroll
  for (int q = 0; q < 4; ++q) {
    int r = y * 4 + q;
    Wt[(size_t)(o0 + r) * INF + k0 + x] = (short)f2bf(tile[x][r]);
  }
}

// ---------- Wh (8192x512 f32) -> Wht (8 x 512 x 1024 bf16) ----------
__global__ __launch_bounds__(256) void transposeWh_kernel(
    const float* __restrict__ Wh, short* __restrict__ Wht) {
  __shared__ float tile[32][33];
  int m0 = blockIdx.x * 32;   // 256 blocks over MTOT
  int o0 = blockIdx.y * 32;   // 16 blocks over OUTF
  int x = threadIdx.x & 31, y = threadIdx.x >> 5;
#pragma unroll
  for (int q = 0; q < 4; ++q) {
    int r = y * 4 + q;
    tile[r][x] = Wh[(size_t)(m0 + r) * OUTF + o0 + x];
  }
  __syncthreads();
  int b = m0 >> 10;
  int i0 = m0 & 1023;
#pragma unroll
  for (int q = 0; q < 4; ++q) {
    int r = y * 4 + q;
    Wht[((size_t)b * OUTF + o0 + r) * NNODE + i0 + x] = (short)f2bf(tile[x][r]);
  }
}

// ---------------- GEMM1: Wh = h @ W + pos_table[positions] ----------------
// M=8192 K=768 N=512, BM=BN=128, BK=32, 4 waves (2x2), each wave 64x64.
__global__ __launch_bounds__(256) void gemm1_kernel(
    const float* __restrict__ h, const short* __restrict__ Wt,
    const int* __restrict__ positions, const float* __restrict__ pos_table,
    float* __restrict__ Wh) {
  __shared__ short As[128][40];  // pad 32->40 shorts (80B stride, 20 banks: 2-way = free)
  __shared__ short Bs[128][40];
  int bid = blockIdx.x;
  int nt = bid & 3, mt = bid >> 2;
  int M0 = mt * 128, N0 = nt * 128;
  int t = threadIdx.x;
  int wave = t >> 6, lane = t & 63;
  int wr = (wave >> 1) * 64, wc = (wave & 1) * 64;
  int l16 = lane & 15, kq = lane >> 4;

  floatx4 acc[4][4] = {};

  for (int k0 = 0; k0 < INF; k0 += 32) {
    // stage A: 128x32 f32 -> bf16. 1024 float4s, 4 per thread.
#pragma unroll
    for (int i = 0; i < 4; ++i) {
      int f = t + i * 256;
      int r = f >> 3, c = (f & 7) * 4;
      float4 v = *(const float4*)&h[(size_t)(M0 + r) * INF + k0 + c];
      union { short s[4]; unsigned long long u; } p;
      p.s[0] = (short)f2bf(v.x); p.s[1] = (short)f2bf(v.y);
      p.s[2] = (short)f2bf(v.z); p.s[3] = (short)f2bf(v.w);
      *(unsigned long long*)&As[r][c] = p.u;
    }
    // stage B: 128x32 bf16 copy. 512 short8s, 2 per thread.
#pragma unroll
    for (int i = 0; i < 2; ++i) {
      int f = t + i * 256;
      int r = f >> 2, c = (f & 3) * 8;
      short8 v = *(const short8*)&Wt[(size_t)(N0 + r) * INF + k0 + c];
      *(short8*)&Bs[r][c] = v;
    }
    __syncthreads();
    short8 af[4], bfr[4];
#pragma unroll
    for (int mi = 0; mi < 4; ++mi) af[mi] = *(const short8*)&As[wr + mi * 16 + l16][kq * 8];
#pragma unroll
    for (int ni = 0; ni < 4; ++ni) bfr[ni] = *(const short8*)&Bs[wc + ni * 16 + l16][kq * 8];
#pragma unroll
    for (int mi = 0; mi < 4; ++mi)
#pragma unroll
      for (int ni = 0; ni < 4; ++ni)
        acc[mi][ni] = __builtin_amdgcn_mfma_f32_16x16x32_bf16(af[mi], bfr[ni], acc[mi][ni], 0, 0, 0);
    __syncthreads();
  }

  // epilogue: C[row= (lane>>4)*4 + j][col = lane&15] + pos_table gather
#pragma unroll
  for (int mi = 0; mi < 4; ++mi) {
#pragma unroll
    for (int j = 0; j < 4; ++j) {
      int row = M0 + wr + mi * 16 + kq * 4 + j;
      int pos = positions[row];
      const float* pt = &pos_table[(size_t)pos * OUTF];
#pragma unroll
      for (int ni = 0; ni < 4; ++ni) {
        int col = N0 + wc + ni * 16 + l16;
        Wh[(size_t)row * OUTF + col] = acc[mi][ni][j] + pt[col];
      }
    }
  }
}

// ---------------- f1/f2: per-row dot with a1/a2 ----------------
__global__ __launch_bounds__(256) void f1f2_kernel(
    const float* __restrict__ Wh, const float* __restrict__ a,
    float* __restrict__ f1, float* __restrict__ f2) {
  int m = blockIdx.x * 4 + (threadIdx.x >> 6);
  int lane = threadIdx.x & 63;
  const float* row = Wh + (size_t)m * OUTF;
  float s1 = 0.f, s2 = 0.f;
#pragma unroll
  for (int i = 0; i < 8; ++i) {
    int c = lane + i * 64;
    float v = row[c];
    s1 += v * a[c];
    s2 += v * a[OUTF + c];
  }
#pragma unroll
  for (int off = 32; off; off >>= 1) {
    s1 += __shfl_xor(s1, off);
    s2 += __shfl_xor(s2, off);
  }
  if (lane == 0) { f1[m] = s1; f2[m] = s2; }
}

// ---------------- masked leaky-relu softmax ----------------
__global__ __launch_bounds__(256) void softmax_kernel(
    const float* __restrict__ f1, const float* __restrict__ f2,
    const int* __restrict__ adj, float* __restrict__ att) {
  int m = blockIdx.x;
  int b = m >> 10;
  int t = threadIdx.x;
  int wave = t >> 6, lane = t & 63;
  __shared__ float red[4];
  float f1v = f1[m];
  const int* adjrow = adj + (size_t)m * NNODE;
  const float* f2b = f2 + b * NNODE;
  float e[4];
#pragma unroll
  for (int q = 0; q < 4; ++q) {
    int j = t + q * 256;
    float x = f1v + f2b[j];
    x = x >= 0.f ? x : 0.2f * x;
    e[q] = adjrow[j] > 0 ? x : -9e15f;
  }
  float mx = fmaxf(fmaxf(e[0], e[1]), fmaxf(e[2], e[3]));
#pragma unroll
  for (int off = 32; off; off >>= 1) mx = fmaxf(mx, __shfl_xor(mx, off));
  if (lane == 0) red[wave] = mx;
  __syncthreads();
  mx = fmaxf(fmaxf(red[0], red[1]), fmaxf(red[2], red[3]));
  __syncthreads();
  float p[4], s = 0.f;
#pragma unroll
  for (int q = 0; q < 4; ++q) { p[q] = expf(e[q] - mx); s += p[q]; }
#pragma unroll
  for (int off = 32; off; off >>= 1) s += __shfl_xor(s, off);
  if (lane == 0) red[wave] = s;
  __syncthreads();
  s = red[0] + red[1] + red[2] + red[3];
  float inv = 1.f / s;
#pragma unroll
  for (int q = 0; q < 4; ++q) att[(size_t)m * NNODE + t + q * 256] = p[q] * inv;
}

// ---------------- PV: h_prime = att @ Wh (per batch) ----------------
// M=8192 K=1024 N=512 with per-batch B panels.
__global__ __launch_bounds__(256) void pv_kernel(
    const float* __restrict__ att, const short* __restrict__ Wht,
    float* __restrict__ hp) {
  __shared__ short As[128][40];
  __shared__ short Bs[128][40];
  int bid = blockIdx.x;
  int nt = bid & 3, mt = bid >> 2;
  int M0 = mt * 128, N0 = nt * 128;
  int b = M0 >> 10;
  const short* Wb = Wht + (size_t)b * OUTF * NNODE;
  int t = threadIdx.x;
  int wave = t >> 6, lane = t & 63;
  int wr = (wave >> 1) * 64, wc = (wave & 1) * 64;
  int l16 = lane & 15, kq = lane >> 4;

  floatx4 acc[4][4] = {};

  for (int k0 = 0; k0 < NNODE; k0 += 32) {
#pragma unroll
    for (int i = 0; i < 4; ++i) {
      int f = t + i * 256;
      int r = f >> 3, c = (f & 7) * 4;
      float4 v = *(const float4*)&att[(size_t)(M0 + r) * NNODE + k0 + c];
      union { short s[4]; unsigned long long u; } p;
      p.s[0] = (short)f2bf(v.x); p.s[1] = (short)f2bf(v.y);
      p.s[2] = (short)f2bf(v.z); p.s[3] = (short)f2bf(v.w);
      *(unsigned long long*)&As[r][c] = p.u;
    }
#pragma unroll
    for (int i = 0; i < 2; ++i) {
      int f = t + i * 256;
      int r = f >> 2, c = (f & 3) * 8;
      short8 v = *(const short8*)&Wb[(size_t)(N0 + r) * NNODE + k0 + c];
      *(short8*)&Bs[r][c] = v;
    }
    __syncthreads();
    short8 af[4], bfr[4];
#pragma unroll
    for (int mi = 0; mi < 4; ++mi) af[mi] = *(const short8*)&As[wr + mi * 16 + l16][kq * 8];
#pragma unroll
    for (int ni = 0; ni < 4; ++ni) bfr[ni] = *(const short8*)&Bs[wc + ni * 16 + l16][kq * 8];
#pragma unroll
    for (int mi = 0; mi < 4; ++mi)
#pragma unroll
      for (int ni = 0; ni < 4; ++ni)
        acc[mi][ni] = __builtin_amdgcn_mfma_f32_16x16x32_bf16(af[mi], bfr[ni], acc[mi][ni], 0, 0, 0);
    __syncthreads();
  }

#pragma unroll
  for (int mi = 0; mi < 4; ++mi) {
#pragma unroll
    for (int j = 0; j < 4; ++j) {
      int row = M0 + wr + mi * 16 + kq * 4 + j;
#pragma unroll
      for (int ni = 0; ni < 4; ++ni) {
        int col = N0 + wc + ni * 16 + l16;
        hp[(size_t)row * OUTF + col] = acc[mi][ni][j];
      }
    }
  }
}

extern "C" void kernel_launch(void* const* d_in, const int* in_sizes, int n_in,
                              void* d_out, int out_size, void* d_ws, size_t ws_size,
                              hipStream_t stream) {
  const float* h = (const float*)d_in[0];
  const int* adj = (const int*)d_in[1];
  const int* positions = (const int*)d_in[2];
  const float* W = (const float*)d_in[3];
  const float* a = (const float*)d_in[4];
  const float* pos_table = (const float*)d_in[5];

  float* hp = (float*)d_out;                       // 8192*512
  float* att = hp + (size_t)MTOT * OUTF;           // 8192*1024

  char* ws = (char*)d_ws;
  short* Wt = (short*)ws;                                       // 512*768*2   = 786432 B
  float* Wh = (float*)(ws + 786432);                            // 8192*512*4  = 16777216 B
  short* Wht = (short*)(ws + 786432 + 16777216);                // 8*512*1024*2= 8388608 B
  float* f1 = (float*)(ws + 786432 + 16777216 + 8388608);       // 8192*4
  float* f2 = f1 + MTOT;                                        // 8192*4

  transposeW_kernel<<<dim3(16, 24), 256, 0, stream>>>(W, Wt);
  gemm1_kernel<<<256, 256, 0, stream>>>(h, Wt, positions, pos_table, Wh);
  f1f2_kernel<<<2048, 256, 0, stream>>>(Wh, a, f1, f2);
  transposeWh_kernel<<<dim3(256, 16), 256, 0, stream>>>(Wh, Wht);
  softmax_kernel<<<8192, 256, 0, stream>>>(f1, f2, adj, att);
  pv_kernel<<<256, 256, 0, stream>>>(att, Wht, hp);
}

// Round 2
// 78.748 us; speedup vs baseline: 1.2485x; 1.2485x over previous
//
#include <hip/hip_runtime.h>
#include <hip/hip_bf16.h>
#include <stdint.h>

#define BATCH 8
#define NNODE 1024
#define INF 768
#define OUTF 512
#define MTOT (BATCH * NNODE) /* 8192 */

typedef __attribute__((ext_vector_type(8))) short short8;
typedef __attribute__((ext_vector_type(4))) short short4v;
typedef __attribute__((ext_vector_type(4))) float floatx4;

__device__ __forceinline__ unsigned short f2bf(float f) {
  union { float f; unsigned u; } v; v.f = f;
  unsigned r = v.u + 0x7fffu + ((v.u >> 16) & 1u);
  return (unsigned short)(r >> 16);
}

__device__ __forceinline__ void gload_lds16(const void* g, void* l) {
  __builtin_amdgcn_global_load_lds(
      (const __attribute__((address_space(1))) void*)g,
      (__attribute__((address_space(3))) void*)l, 16, 0, 0);
}

// ---------------- W (768x512 f32) -> Wt (512x768 bf16) ----------------
__global__ __launch_bounds__(256) void transposeW_kernel(
    const float* __restrict__ W, short* __restrict__ Wt) {
  __shared__ float tile[32][33];
  int o0 = blockIdx.x * 32;
  int k0 = blockIdx.y * 32;
  int x = threadIdx.x & 31, y = threadIdx.x >> 5;
#pragma unroll
  for (int q = 0; q < 4; ++q) {
    int r = y * 4 + q;
    tile[r][x] = W[(size_t)(k0 + r) * OUTF + o0 + x];
  }
  __syncthreads();
#pragma unroll
  for (int q = 0; q < 4; ++q) {
    int r = y * 4 + q;
    Wt[(size_t)(o0 + r) * INF + k0 + x] = (short)f2bf(tile[x][r]);
  }
}

// ---------------- h (8192x768 f32) -> hbf (bf16) ----------------
__global__ __launch_bounds__(256) void h2bf_kernel(
    const float* __restrict__ h, short* __restrict__ hbf) {
  size_t i = ((size_t)blockIdx.x * 256 + threadIdx.x) * 8;
  float4 v0 = *(const float4*)&h[i];
  float4 v1 = *(const float4*)&h[i + 4];
  short8 o;
  o[0] = (short)f2bf(v0.x); o[1] = (short)f2bf(v0.y);
  o[2] = (short)f2bf(v0.z); o[3] = (short)f2bf(v0.w);
  o[4] = (short)f2bf(v1.x); o[5] = (short)f2bf(v1.y);
  o[6] = (short)f2bf(v1.z); o[7] = (short)f2bf(v1.w);
  *(short8*)&hbf[i] = o;
}

// ---------- Wh (8192x512 f32) -> Wht (8 x 512 x 1024 bf16) ----------
__global__ __launch_bounds__(256) void transposeWh_kernel(
    const float* __restrict__ Wh, short* __restrict__ Wht) {
  __shared__ float tile[32][33];
  int m0 = blockIdx.x * 32;
  int o0 = blockIdx.y * 32;
  int x = threadIdx.x & 31, y = threadIdx.x >> 5;
#pragma unroll
  for (int q = 0; q < 4; ++q) {
    int r = y * 4 + q;
    tile[r][x] = Wh[(size_t)(m0 + r) * OUTF + o0 + x];
  }
  __syncthreads();
  int b = m0 >> 10;
  int i0 = m0 & 1023;
#pragma unroll
  for (int q = 0; q < 4; ++q) {
    int r = y * 4 + q;
    Wht[((size_t)b * OUTF + o0 + r) * NNODE + i0 + x] = (short)f2bf(tile[x][r]);
  }
}

// ---------------- GEMM1: Wh = h @ W + pos_table[positions] ----------------
// M=8192 K=768 N=512, BM=BN=128, BK=64, 8 waves (2x4), wave tile 64x32.
// LDS layout: [row][chunk] bf16, chunk=16B; stored swizzled: LDS(row, c^(row&7))
// holds global chunk (row, c). Staged via global_load_lds (linear dest,
// inverse-swizzled per-lane global source).
__global__ __launch_bounds__(512) void gemm1_kernel(
    const short* __restrict__ hbf, const short* __restrict__ Wt,
    const int* __restrict__ positions, const float* __restrict__ pos_table,
    float* __restrict__ Wh) {
  __shared__ short As[128 * 64];
  __shared__ short Bs[128 * 64];
  int bid = blockIdx.x;
  int nt = bid & 3, mt = bid >> 2;
  int M0 = mt * 128, N0 = nt * 128;
  int t = threadIdx.x;
  int wv = t >> 6, lane = t & 63;
  int wr = (wv >> 2) * 64, wc = (wv & 3) * 32;
  int l16 = lane & 15, kq = lane >> 4;

  floatx4 acc[4][2] = {};

  for (int k0 = 0; k0 < INF; k0 += 64) {
#pragma unroll
    for (int i = 0; i < 2; ++i) {
      int q = wv * 64 + lane + i * 512;
      int row = q >> 3;
      int cg = (q & 7) ^ (row & 7);
      gload_lds16(&hbf[(size_t)(M0 + row) * INF + k0 + cg * 8],
                  &As[(wv * 64 + i * 512) * 8]);
      gload_lds16(&Wt[(size_t)(N0 + row) * INF + k0 + cg * 8],
                  &Bs[(wv * 64 + i * 512) * 8]);
    }
    __syncthreads();
#pragma unroll
    for (int ks = 0; ks < 2; ++ks) {
      short8 af[4], bfv[2];
#pragma unroll
      for (int mi = 0; mi < 4; ++mi) {
        int r = wr + mi * 16 + l16;
        int c = ks * 4 + kq;
        af[mi] = *(const short8*)&As[r * 64 + ((c ^ (r & 7)) * 8)];
      }
#pragma unroll
      for (int ni = 0; ni < 2; ++ni) {
        int r = wc + ni * 16 + l16;
        int c = ks * 4 + kq;
        bfv[ni] = *(const short8*)&Bs[r * 64 + ((c ^ (r & 7)) * 8)];
      }
#pragma unroll
      for (int mi = 0; mi < 4; ++mi)
#pragma unroll
        for (int ni = 0; ni < 2; ++ni)
          acc[mi][ni] = __builtin_amdgcn_mfma_f32_16x16x32_bf16(af[mi], bfv[ni], acc[mi][ni], 0, 0, 0);
    }
    __syncthreads();
  }

#pragma unroll
  for (int mi = 0; mi < 4; ++mi) {
#pragma unroll
    for (int j = 0; j < 4; ++j) {
      int row = M0 + wr + mi * 16 + kq * 4 + j;
      int pos = positions[row];
#pragma unroll
      for (int ni = 0; ni < 2; ++ni) {
        int col = N0 + wc + ni * 16 + l16;
        Wh[(size_t)row * OUTF + col] = acc[mi][ni][j] + pos_table[(size_t)pos * OUTF + col];
      }
    }
  }
}

// ---------------- f1/f2: per-row dot with a1/a2 ----------------
__global__ __launch_bounds__(256) void f1f2_kernel(
    const float* __restrict__ Wh, const float* __restrict__ a,
    float* __restrict__ f1, float* __restrict__ f2) {
  int m = blockIdx.x * 4 + (threadIdx.x >> 6);
  int lane = threadIdx.x & 63;
  const float4* row = (const float4*)(Wh + (size_t)m * OUTF);
  const float4* a1 = (const float4*)a;
  const float4* a2 = (const float4*)(a + OUTF);
  float s1 = 0.f, s2 = 0.f;
#pragma unroll
  for (int i = 0; i < 2; ++i) {
    int c = lane + i * 64;
    float4 v = row[c], w1 = a1[c], w2 = a2[c];
    s1 += v.x * w1.x + v.y * w1.y + v.z * w1.z + v.w * w1.w;
    s2 += v.x * w2.x + v.y * w2.y + v.z * w2.z + v.w * w2.w;
  }
#pragma unroll
  for (int off = 32; off; off >>= 1) {
    s1 += __shfl_xor(s1, off);
    s2 += __shfl_xor(s2, off);
  }
  if (lane == 0) { f1[m] = s1; f2[m] = s2; }
}

// ---------------- masked leaky-relu softmax (f32 out + bf16 copy) ----------------
__global__ __launch_bounds__(256) void softmax_kernel(
    const float* __restrict__ f1, const float* __restrict__ f2,
    const int* __restrict__ adj, float* __restrict__ att,
    short* __restrict__ attbf) {
  int m = blockIdx.x;
  int b = m >> 10;
  int t = threadIdx.x;
  int wave = t >> 6, lane = t & 63;
  __shared__ float red[4];
  float f1v = f1[m];
  int4 av = ((const int4*)(adj + (size_t)m * NNODE))[t];
  float4 fv = ((const float4*)(f2 + b * NNODE))[t];
  float e[4];
  {
    float x;
    x = f1v + fv.x; x = x >= 0.f ? x : 0.2f * x; e[0] = av.x > 0 ? x : -9e15f;
    x = f1v + fv.y; x = x >= 0.f ? x : 0.2f * x; e[1] = av.y > 0 ? x : -9e15f;
    x = f1v + fv.z; x = x >= 0.f ? x : 0.2f * x; e[2] = av.z > 0 ? x : -9e15f;
    x = f1v + fv.w; x = x >= 0.f ? x : 0.2f * x; e[3] = av.w > 0 ? x : -9e15f;
  }
  float mx = fmaxf(fmaxf(e[0], e[1]), fmaxf(e[2], e[3]));
#pragma unroll
  for (int off = 32; off; off >>= 1) mx = fmaxf(mx, __shfl_xor(mx, off));
  if (lane == 0) red[wave] = mx;
  __syncthreads();
  mx = fmaxf(fmaxf(red[0], red[1]), fmaxf(red[2], red[3]));
  __syncthreads();
  float p[4], s = 0.f;
#pragma unroll
  for (int q = 0; q < 4; ++q) { p[q] = expf(e[q] - mx); s += p[q]; }
#pragma unroll
  for (int off = 32; off; off >>= 1) s += __shfl_xor(s, off);
  if (lane == 0) red[wave] = s;
  __syncthreads();
  s = red[0] + red[1] + red[2] + red[3];
  float inv = 1.f / s;
  float4 o = make_float4(p[0] * inv, p[1] * inv, p[2] * inv, p[3] * inv);
  ((float4*)(att + (size_t)m * NNODE))[t] = o;
  short4v ob;
  ob[0] = (short)f2bf(o.x); ob[1] = (short)f2bf(o.y);
  ob[2] = (short)f2bf(o.z); ob[3] = (short)f2bf(o.w);
  ((short4v*)(attbf + (size_t)m * NNODE))[t] = ob;
}

// ---------------- PV: h_prime = att @ Wh (per batch) ----------------
// M=8192 K=1024 N=512, BM=BN=128, BK=64, 8 waves (2x4), wave tile 64x32.
__global__ __launch_bounds__(512) void pv_kernel(
    const short* __restrict__ attbf, const short* __restrict__ Wht,
    float* __restrict__ hp) {
  __shared__ short As[128 * 64];
  __shared__ short Bs[128 * 64];
  int bid = blockIdx.x;
  int nt = bid & 3, mt = bid >> 2;
  int M0 = mt * 128, N0 = nt * 128;
  int b = M0 >> 10;
  const short* Wb = Wht + (size_t)b * OUTF * NNODE;
  int t = threadIdx.x;
  int wv = t >> 6, lane = t & 63;
  int wr = (wv >> 2) * 64, wc = (wv & 3) * 32;
  int l16 = lane & 15, kq = lane >> 4;

  floatx4 acc[4][2] = {};

  for (int k0 = 0; k0 < NNODE; k0 += 64) {
#pragma unroll
    for (int i = 0; i < 2; ++i) {
      int q = wv * 64 + lane + i * 512;
      int row = q >> 3;
      int cg = (q & 7) ^ (row & 7);
      gload_lds16(&attbf[(size_t)(M0 + row) * NNODE + k0 + cg * 8],
                  &As[(wv * 64 + i * 512) * 8]);
      gload_lds16(&Wb[(size_t)(N0 + row) * NNODE + k0 + cg * 8],
                  &Bs[(wv * 64 + i * 512) * 8]);
    }
    __syncthreads();
#pragma unroll
    for (int ks = 0; ks < 2; ++ks) {
      short8 af[4], bfv[2];
#pragma unroll
      for (int mi = 0; mi < 4; ++mi) {
        int r = wr + mi * 16 + l16;
        int c = ks * 4 + kq;
        af[mi] = *(const short8*)&As[r * 64 + ((c ^ (r & 7)) * 8)];
      }
#pragma unroll
      for (int ni = 0; ni < 2; ++ni) {
        int r = wc + ni * 16 + l16;
        int c = ks * 4 + kq;
        bfv[ni] = *(const short8*)&Bs[r * 64 + ((c ^ (r & 7)) * 8)];
      }
#pragma unroll
      for (int mi = 0; mi < 4; ++mi)
#pragma unroll
        for (int ni = 0; ni < 2; ++ni)
          acc[mi][ni] = __builtin_amdgcn_mfma_f32_16x16x32_bf16(af[mi], bfv[ni], acc[mi][ni], 0, 0, 0);
    }
    __syncthreads();
  }

#pragma unroll
  for (int mi = 0; mi < 4; ++mi) {
#pragma unroll
    for (int j = 0; j < 4; ++j) {
      int row = M0 + wr + mi * 16 + kq * 4 + j;
#pragma unroll
      for (int ni = 0; ni < 2; ++ni) {
        int col = N0 + wc + ni * 16 + l16;
        hp[(size_t)row * OUTF + col] = acc[mi][ni][j];
      }
    }
  }
}

extern "C" void kernel_launch(void* const* d_in, const int* in_sizes, int n_in,
                              void* d_out, int out_size, void* d_ws, size_t ws_size,
                              hipStream_t stream) {
  const float* h = (const float*)d_in[0];
  const int* adj = (const int*)d_in[1];
  const int* positions = (const int*)d_in[2];
  const float* W = (const float*)d_in[3];
  const float* a = (const float*)d_in[4];
  const float* pos_table = (const float*)d_in[5];

  float* hp = (float*)d_out;                       // 8192*512
  float* att = hp + (size_t)MTOT * OUTF;           // 8192*1024

  char* ws = (char*)d_ws;
  short* Wt = (short*)ws;                                       // 786432 B
  float* Wh = (float*)(ws + 786432);                            // 16777216 B
  short* Wht = (short*)(ws + 786432 + 16777216);                // 8388608 B
  float* f1 = (float*)(ws + 786432 + 16777216 + 8388608);       // 32768 B
  float* f2 = f1 + MTOT;                                        // 32768 B
  // union region: hbf (12.6 MB, used before softmax) / attbf (16.8 MB, after)
  short* hbf = (short*)(ws + 786432 + 16777216 + 8388608 + 65536);
  short* attbf = hbf;

  transposeW_kernel<<<dim3(16, 24), 256, 0, stream>>>(W, Wt);
  h2bf_kernel<<<3072, 256, 0, stream>>>(h, hbf);
  gemm1_kernel<<<256, 512, 0, stream>>>(hbf, Wt, positions, pos_table, Wh);
  f1f2_kernel<<<2048, 256, 0, stream>>>(Wh, a, f1, f2);
  transposeWh_kernel<<<dim3(256, 16), 256, 0, stream>>>(Wh, Wht);
  softmax_kernel<<<8192, 256, 0, stream>>>(f1, f2, adj, att, attbf);
  pv_kernel<<<256, 512, 0, stream>>>(attbf, Wht, hp);
}

// Round 3
// 58.402 us; speedup vs baseline: 1.6835x; 1.3484x over previous
//
#include <hip/hip_runtime.h>
#include <stdint.h>

#define BATCH 8
#define NNODE 1024
#define INF 768
#define OUTF 512
#define MTOT (BATCH * NNODE) /* 8192 */

typedef __attribute__((ext_vector_type(8))) short short8;
typedef __attribute__((ext_vector_type(4))) short short4v;
typedef __attribute__((ext_vector_type(4))) float floatx4;

__device__ __forceinline__ unsigned short f2bf(float f) {
  union { float f; unsigned u; } v; v.f = f;
  unsigned r = v.u + 0x7fffu + ((v.u >> 16) & 1u);
  return (unsigned short)(r >> 16);
}

__device__ __forceinline__ void gload_lds16(const void* g, void* l) {
  __builtin_amdgcn_global_load_lds(
      (const __attribute__((address_space(1))) void*)g,
      (__attribute__((address_space(3))) void*)l, 16, 0, 0);
}

// ------------- prep: h->bf16 (+zero f12), W -> Wt (512x768 bf16) -------------
__global__ __launch_bounds__(256) void prep_kernel(
    const float* __restrict__ h, const float* __restrict__ W,
    short* __restrict__ hbf, short* __restrict__ Wt, float* __restrict__ f12) {
  __shared__ float tile[32][33];
  int bid = blockIdx.x;
  int t = threadIdx.x;
  if (bid < 3072) {
    size_t i = ((size_t)bid * 256 + t) * 8;
    float4 v0 = *(const float4*)&h[i];
    float4 v1 = *(const float4*)&h[i + 4];
    short8 o;
    o[0] = (short)f2bf(v0.x); o[1] = (short)f2bf(v0.y);
    o[2] = (short)f2bf(v0.z); o[3] = (short)f2bf(v0.w);
    o[4] = (short)f2bf(v1.x); o[5] = (short)f2bf(v1.y);
    o[6] = (short)f2bf(v1.z); o[7] = (short)f2bf(v1.w);
    *(short8*)&hbf[i] = o;
    if (bid < 16) {
      float4 z = make_float4(0.f, 0.f, 0.f, 0.f);
      *(float4*)&f12[bid * 1024 + t * 4] = z;
    }
  } else {
    int tb = bid - 3072;             // 384 tiles: 16 (o) x 24 (k)
    int o0 = (tb & 15) * 32;
    int k0 = (tb >> 4) * 32;
    int x = t & 31, y = t >> 5;
#pragma unroll
    for (int q = 0; q < 4; ++q) {
      int r = y * 4 + q;
      tile[r][x] = W[(size_t)(k0 + r) * OUTF + o0 + x];
    }
    __syncthreads();
#pragma unroll
    for (int q = 0; q < 4; ++q) {
      int r = y * 4 + q;
      Wt[(size_t)(o0 + r) * INF + k0 + x] = (short)f2bf(tile[x][r]);
    }
  }
}

// ---- GEMM1 fused: Wh = h@W + pos  ->  Wht (bf16, transposed) + f1/f2 ----
// M=8192 K=768 N=512, BM=BN=128, BK=64, 8 waves (2x4), wave tile 64x32.
// 2-phase double-buffered K-loop; epilogue produces Wht and atomic f1/f2.
__global__ __launch_bounds__(512) void gemm1_kernel(
    const short* __restrict__ hbf, const short* __restrict__ Wt,
    const int* __restrict__ positions, const float* __restrict__ pos_table,
    const float* __restrict__ a, float* __restrict__ f12,
    short* __restrict__ Wht) {
  __shared__ short smem[4][8192];   // A0,B0,A1,B1 (16KB each)
  int bid0 = blockIdx.x;
  int bid = (bid0 & 7) * 32 + (bid0 >> 3);   // XCD swizzle (256 % 8 == 0)
  int nt = bid & 3, mt = bid >> 2;
  int M0 = mt * 128, N0 = nt * 128;
  int t = threadIdx.x;
  int wv = t >> 6, lane = t & 63;
  int wr = (wv >> 2) * 64, wc = (wv & 3) * 32;
  int l16 = lane & 15, kq = lane >> 4;

  floatx4 acc[4][2] = {};

  auto stage = [&](int buf, int kt) {
#pragma unroll
    for (int i = 0; i < 2; ++i) {
      int q = wv * 64 + lane + i * 512;
      int row = q >> 3;
      int cg = (q & 7) ^ (row & 7);   // inverse-swizzled global source
      gload_lds16(&hbf[(size_t)(M0 + row) * INF + kt * 64 + cg * 8],
                  &smem[buf * 2][(wv * 64 + i * 512) * 8]);
      gload_lds16(&Wt[(size_t)(N0 + row) * INF + kt * 64 + cg * 8],
                  &smem[buf * 2 + 1][(wv * 64 + i * 512) * 8]);
    }
  };

  stage(0, 0);
  __syncthreads();
  int cur = 0;
  for (int kt = 0; kt < 12; ++kt) {
    if (kt < 11) stage(cur ^ 1, kt + 1);
    const short* As = smem[cur * 2];
    const short* Bs = smem[cur * 2 + 1];
#pragma unroll
    for (int ks = 0; ks < 2; ++ks) {
      short8 af[4], bfv[2];
#pragma unroll
      for (int mi = 0; mi < 4; ++mi) {
        int r = wr + mi * 16 + l16;
        af[mi] = *(const short8*)&As[r * 64 + (((ks * 4 + kq) ^ (r & 7)) * 8)];
      }
#pragma unroll
      for (int ni = 0; ni < 2; ++ni) {
        int r = wc + ni * 16 + l16;
        bfv[ni] = *(const short8*)&Bs[r * 64 + (((ks * 4 + kq) ^ (r & 7)) * 8)];
      }
#pragma unroll
      for (int mi = 0; mi < 4; ++mi)
#pragma unroll
        for (int ni = 0; ni < 2; ++ni)
          acc[mi][ni] = __builtin_amdgcn_mfma_f32_16x16x32_bf16(af[mi], bfv[ni], acc[mi][ni], 0, 0, 0);
    }
    __syncthreads();
    cur ^= 1;
  }

  // ---- epilogue ----
  int oc0 = N0 + wc + l16;
  int oc1 = oc0 + 16;
  // (1) add positional encoding into accumulators (Wh values, f32)
#pragma unroll
  for (int mi = 0; mi < 4; ++mi)
#pragma unroll
    for (int j = 0; j < 4; ++j) {
      int row = M0 + wr + mi * 16 + kq * 4 + j;
      int pos = positions[row];
      acc[mi][0][j] += pos_table[(size_t)pos * OUTF + oc0];
      acc[mi][1][j] += pos_table[(size_t)pos * OUTF + oc1];
    }
  // (2) transposed bf16 tile -> LDS (row stride 136 shorts spreads banks)
  short* T = &smem[0][0];   // 128*136 shorts = 34.8KB of the 64KB
#pragma unroll
  for (int mi = 0; mi < 4; ++mi)
#pragma unroll
    for (int ni = 0; ni < 2; ++ni)
#pragma unroll
      for (int j = 0; j < 4; ++j)
        T[(wc + ni * 16 + l16) * 136 + wr + mi * 16 + kq * 4 + j] =
            (short)f2bf(acc[mi][ni][j]);
  // (3) f1/f2 partials + 16-lane butterfly transpose-reduce, one atomic/lane
  float a10 = a[oc0], a11 = a[oc1];
  float a20 = a[OUTF + oc0], a21 = a[OUTF + oc1];
  float v1[16], v2[16];
#pragma unroll
  for (int mi = 0; mi < 4; ++mi)
#pragma unroll
    for (int j = 0; j < 4; ++j) {
      v1[mi * 4 + j] = acc[mi][0][j] * a10 + acc[mi][1][j] * a11;
      v2[mi * 4 + j] = acc[mi][0][j] * a20 + acc[mi][1][j] * a21;
    }
#pragma unroll
  for (int mlen = 8; mlen >= 1; mlen >>= 1) {
    bool hi = (l16 & mlen) != 0;
#pragma unroll
    for (int i = 0; i < mlen; ++i) {
      float k1 = hi ? v1[mlen + i] : v1[i];
      float s1 = hi ? v1[i] : v1[mlen + i];
      float k2 = hi ? v2[mlen + i] : v2[i];
      float s2 = hi ? v2[i] : v2[mlen + i];
      v1[i] = k1 + __shfl_xor(s1, mlen);
      v2[i] = k2 + __shfl_xor(s2, mlen);
    }
  }
  {
    // lane (kq,l16) owns row_loc = wr + (l16>>2)*16 + kq*4 + (l16&3)
    int rrow = M0 + wr + (l16 >> 2) * 16 + kq * 4 + (l16 & 3);
    atomicAdd(&f12[rrow], v1[0]);
    atomicAdd(&f12[MTOT + rrow], v2[0]);
  }
  // (4) coalesced Wht store
  __syncthreads();
  int bb = M0 >> 10, i0 = M0 & 1023;
#pragma unroll
  for (int i = 0; i < 4; ++i) {
    int c = t + i * 512;          // 2048 chunks of 8 shorts
    int row = c >> 4;             // o-row in tile
    int mc = (c & 15) * 8;
    short8 vv = *(const short8*)&T[row * 136 + mc];
    *(short8*)&Wht[((size_t)bb * OUTF + N0 + row) * NNODE + i0 + mc] = vv;
  }
}

// ---------------- masked leaky-relu softmax (f32 out + bf16 copy) ----------------
__global__ __launch_bounds__(256) void softmax_kernel(
    const float* __restrict__ f1, const float* __restrict__ f2,
    const int* __restrict__ adj, float* __restrict__ att,
    short* __restrict__ attbf) {
  int m = blockIdx.x;
  int b = m >> 10;
  int t = threadIdx.x;
  int wave = t >> 6, lane = t & 63;
  __shared__ float red[4];
  float f1v = f1[m];
  int4 av = ((const int4*)(adj + (size_t)m * NNODE))[t];
  float4 fv = ((const float4*)(f2 + b * NNODE))[t];
  float e[4];
  {
    float x;
    x = f1v + fv.x; x = x >= 0.f ? x : 0.2f * x; e[0] = av.x > 0 ? x : -9e15f;
    x = f1v + fv.y; x = x >= 0.f ? x : 0.2f * x; e[1] = av.y > 0 ? x : -9e15f;
    x = f1v + fv.z; x = x >= 0.f ? x : 0.2f * x; e[2] = av.z > 0 ? x : -9e15f;
    x = f1v + fv.w; x = x >= 0.f ? x : 0.2f * x; e[3] = av.w > 0 ? x : -9e15f;
  }
  float mx = fmaxf(fmaxf(e[0], e[1]), fmaxf(e[2], e[3]));
#pragma unroll
  for (int off = 32; off; off >>= 1) mx = fmaxf(mx, __shfl_xor(mx, off));
  if (lane == 0) red[wave] = mx;
  __syncthreads();
  mx = fmaxf(fmaxf(red[0], red[1]), fmaxf(red[2], red[3]));
  __syncthreads();
  float p[4], s = 0.f;
#pragma unroll
  for (int q = 0; q < 4; ++q) { p[q] = expf(e[q] - mx); s += p[q]; }
#pragma unroll
  for (int off = 32; off; off >>= 1) s += __shfl_xor(s, off);
  if (lane == 0) red[wave] = s;
  __syncthreads();
  s = red[0] + red[1] + red[2] + red[3];
  float inv = 1.f / s;
  float4 o = make_float4(p[0] * inv, p[1] * inv, p[2] * inv, p[3] * inv);
  ((float4*)(att + (size_t)m * NNODE))[t] = o;
  short4v ob;
  ob[0] = (short)f2bf(o.x); ob[1] = (short)f2bf(o.y);
  ob[2] = (short)f2bf(o.z); ob[3] = (short)f2bf(o.w);
  ((short4v*)(attbf + (size_t)m * NNODE))[t] = ob;
}

// ---------------- PV: h_prime = att @ Wh (per batch) ----------------
// M=8192 K=1024 N=512, BM=BN=128, BK=64, 8 waves (2x4), 2-phase dbuf.
__global__ __launch_bounds__(512) void pv_kernel(
    const short* __restrict__ attbf, const short* __restrict__ Wht,
    float* __restrict__ hp) {
  __shared__ short smem[4][8192];
  int bid0 = blockIdx.x;
  int bid = (bid0 & 7) * 32 + (bid0 >> 3);   // XCD swizzle: one batch per XCD
  int nt = bid & 3, mt = bid >> 2;
  int M0 = mt * 128, N0 = nt * 128;
  const short* Wb = Wht + (size_t)(M0 >> 10) * OUTF * NNODE;
  int t = threadIdx.x;
  int wv = t >> 6, lane = t & 63;
  int wr = (wv >> 2) * 64, wc = (wv & 3) * 32;
  int l16 = lane & 15, kq = lane >> 4;

  floatx4 acc[4][2] = {};

  auto stage = [&](int buf, int kt) {
#pragma unroll
    for (int i = 0; i < 2; ++i) {
      int q = wv * 64 + lane + i * 512;
      int row = q >> 3;
      int cg = (q & 7) ^ (row & 7);
      gload_lds16(&attbf[(size_t)(M0 + row) * NNODE + kt * 64 + cg * 8],
                  &smem[buf * 2][(wv * 64 + i * 512) * 8]);
      gload_lds16(&Wb[(size_t)(N0 + row) * NNODE + kt * 64 + cg * 8],
                  &smem[buf * 2 + 1][(wv * 64 + i * 512) * 8]);
    }
  };

  stage(0, 0);
  __syncthreads();
  int cur = 0;
  for (int kt = 0; kt < 16; ++kt) {
    if (kt < 15) stage(cur ^ 1, kt + 1);
    const short* As = smem[cur * 2];
    const short* Bs = smem[cur * 2 + 1];
#pragma unroll
    for (int ks = 0; ks < 2; ++ks) {
      short8 af[4], bfv[2];
#pragma unroll
      for (int mi = 0; mi < 4; ++mi) {
        int r = wr + mi * 16 + l16;
        af[mi] = *(const short8*)&As[r * 64 + (((ks * 4 + kq) ^ (r & 7)) * 8)];
      }
#pragma unroll
      for (int ni = 0; ni < 2; ++ni) {
        int r = wc + ni * 16 + l16;
        bfv[ni] = *(const short8*)&Bs[r * 64 + (((ks * 4 + kq) ^ (r & 7)) * 8)];
      }
#pragma unroll
      for (int mi = 0; mi < 4; ++mi)
#pragma unroll
        for (int ni = 0; ni < 2; ++ni)
          acc[mi][ni] = __builtin_amdgcn_mfma_f32_16x16x32_bf16(af[mi], bfv[ni], acc[mi][ni], 0, 0, 0);
    }
    __syncthreads();
    cur ^= 1;
  }

#pragma unroll
  for (int mi = 0; mi < 4; ++mi) {
#pragma unroll
    for (int j = 0; j < 4; ++j) {
      int row = M0 + wr + mi * 16 + kq * 4 + j;
#pragma unroll
      for (int ni = 0; ni < 2; ++ni) {
        int col = N0 + wc + ni * 16 + l16;
        hp[(size_t)row * OUTF + col] = acc[mi][ni][j];
      }
    }
  }
}

extern "C" void kernel_launch(void* const* d_in, const int* in_sizes, int n_in,
                              void* d_out, int out_size, void* d_ws, size_t ws_size,
                              hipStream_t stream) {
  const float* h = (const float*)d_in[0];
  const int* adj = (const int*)d_in[1];
  const int* positions = (const int*)d_in[2];
  const float* W = (const float*)d_in[3];
  const float* a = (const float*)d_in[4];
  const float* pos_table = (const float*)d_in[5];

  float* hp = (float*)d_out;                       // 8192*512
  float* att = hp + (size_t)MTOT * OUTF;           // 8192*1024

  char* ws = (char*)d_ws;
  short* Wt = (short*)ws;                                   // 786432 B
  short* Wht = (short*)(ws + 786432);                       // 8388608 B
  float* f12 = (float*)(ws + 786432 + 8388608);             // 65536 B
  short* hbf = (short*)(ws + 786432 + 8388608 + 65536);     // 16777216 B (union)
  short* attbf = hbf;   // hbf dead after gemm1; attbf written by softmax

  prep_kernel<<<3456, 256, 0, stream>>>(h, W, hbf, Wt, f12);
  gemm1_kernel<<<256, 512, 0, stream>>>(hbf, Wt, positions, pos_table, a, f12, Wht);
  softmax_kernel<<<8192, 256, 0, stream>>>(f12, f12 + MTOT, adj, att, attbf);
  pv_kernel<<<256, 512, 0, stream>>>(attbf, Wht, hp);
}